// Round 1
// baseline (277.445 us; speedup 1.0000x reference)
//
#include <hip/hip_runtime.h>
#include <math.h>

// MLPTexture3D: 5-level dense-grid trilinear encoding (2 feats/level -> 10)
// + MLP 10->32->32->3 (no bias, relu, relu, sigmoid*(max-min)+min).
//
// Inputs (setup_inputs order):
//   0: texc  [2048,2048,3] f32
//   1: table [533601,2]    f32
//   2: W0    [32,10]       f32
//   3: W1    [32,32]       f32
//   4: W2    [3,32]        f32
//   5: min_val [3] f32
//   6: max_val [3] f32
//   7: frame_id (unused)
// Output: [2048,2048,3] f32

namespace {

__device__ __forceinline__ float clamp01(float v) {
    return fminf(fmaxf(v, 0.0f), 1.0f);
}

__global__ __launch_bounds__(256) void mlptex_kernel(
    const float* __restrict__ texc,
    const float* __restrict__ table,   // [533601,2]
    const float* __restrict__ W0,      // [32,10]
    const float* __restrict__ W1,      // [32,32]
    const float* __restrict__ W2,      // [3,32]
    const float* __restrict__ minv,    // [3]
    const float* __restrict__ maxv,    // [3]
    float* __restrict__ out,           // [N,3]
    int N)
{
    const int i = blockIdx.x * blockDim.x + threadIdx.x;
    if (i >= N) return;

    float x = texc[3*i+0];
    float y = texc[3*i+1];
    float z = texc[3*i+2];
    // (v - bbox_min) / (bbox_max - bbox_min); bbox_min=(.6,.6,.2),
    // bbox_max-bbox_min = (-1.4,-1.8,-0.4)
    x = clamp01((x - 0.6f) * (-1.0f/1.4f));
    y = clamp01((y - 0.6f) * (-1.0f/1.8f));
    z = clamp01((z - 0.2f) * (-1.0f/0.4f));

    const float2* __restrict__ tab = reinterpret_cast<const float2*>(table);

    const int RESL[5]  = {16, 23, 33, 48, 70};
    const int OFFSL[5] = {0, 4913, 18737, 58041, 175690};

    float p[10];

    #pragma unroll
    for (int l = 0; l < 5; ++l) {
        const int r = RESL[l];
        const int g = r + 1;
        const float rf = (float)r;
        float px = x * rf, py = y * rf, pz = z * rf;
        float fx = fminf(floorf(px), rf - 1.0f);
        float fy = fminf(floorf(py), rf - 1.0f);
        float fz = fminf(floorf(pz), rf - 1.0f);
        float tx = px - fx, ty = py - fy, tz = pz - fz;
        int ix = (int)fx, iy = (int)fy, iz = (int)fz;
        int base = (ix * g + iy) * g + iz + OFFSL[l];

        // 8 corner fetches (float2 each, 8B-aligned)
        float2 c000 = tab[base];
        float2 c001 = tab[base + 1];
        float2 c010 = tab[base + g];
        float2 c011 = tab[base + g + 1];
        float2 c100 = tab[base + g*g];
        float2 c101 = tab[base + g*g + 1];
        float2 c110 = tab[base + g*g + g];
        float2 c111 = tab[base + g*g + g + 1];

        float sx = 1.0f - tx, sy = 1.0f - ty, sz = 1.0f - tz;
        float w00 = sy*sz, w01 = sy*tz, w10 = ty*sz, w11 = ty*tz;
        float a00 = sx*w00, a01 = sx*w01, a10 = sx*w10, a11 = sx*w11;
        float b00 = tx*w00, b01 = tx*w01, b10 = tx*w10, b11 = tx*w11;

        float f0, f1;
        f0  = a00*c000.x;            f1  = a00*c000.y;
        f0  = fmaf(a01, c001.x, f0); f1  = fmaf(a01, c001.y, f1);
        f0  = fmaf(a10, c010.x, f0); f1  = fmaf(a10, c010.y, f1);
        f0  = fmaf(a11, c011.x, f0); f1  = fmaf(a11, c011.y, f1);
        f0  = fmaf(b00, c100.x, f0); f1  = fmaf(b00, c100.y, f1);
        f0  = fmaf(b01, c101.x, f0); f1  = fmaf(b01, c101.y, f1);
        f0  = fmaf(b10, c110.x, f0); f1  = fmaf(b10, c110.y, f1);
        f0  = fmaf(b11, c111.x, f0); f1  = fmaf(b11, c111.y, f1);

        p[2*l+0] = f0;
        p[2*l+1] = f1;
    }

    // MLP: weights are wave-uniform loads -> expect s_load + SGPR-operand fmac
    float h0[32];
    #pragma unroll
    for (int j = 0; j < 32; ++j) {
        float acc = 0.0f;
        #pragma unroll
        for (int k = 0; k < 10; ++k) acc = fmaf(p[k], W0[j*10+k], acc);
        h0[j] = fmaxf(acc, 0.0f);
    }
    float h1[32];
    #pragma unroll
    for (int j = 0; j < 32; ++j) {
        float acc = 0.0f;
        #pragma unroll
        for (int k = 0; k < 32; ++k) acc = fmaf(h0[k], W1[j*32+k], acc);
        h1[j] = fmaxf(acc, 0.0f);
    }
    #pragma unroll
    for (int j = 0; j < 3; ++j) {
        float acc = 0.0f;
        #pragma unroll
        for (int k = 0; k < 32; ++k) acc = fmaf(h1[k], W2[j*32+k], acc);
        float s = 1.0f / (1.0f + __expf(-acc));
        out[3*i+j] = fmaf(s, maxv[j] - minv[j], minv[j]);
    }
}

} // anonymous namespace

extern "C" void kernel_launch(void* const* d_in, const int* in_sizes, int n_in,
                              void* d_out, int out_size, void* d_ws, size_t ws_size,
                              hipStream_t stream) {
    const float* texc  = (const float*)d_in[0];
    const float* table = (const float*)d_in[1];
    const float* W0    = (const float*)d_in[2];
    const float* W1    = (const float*)d_in[3];
    const float* W2    = (const float*)d_in[4];
    const float* minv  = (const float*)d_in[5];
    const float* maxv  = (const float*)d_in[6];
    float* out = (float*)d_out;

    const int N = in_sizes[0] / 3;   // 4,194,304 points
    const int threads = 256;
    const int blocks = (N + threads - 1) / threads;
    mlptex_kernel<<<blocks, threads, 0, stream>>>(texc, table, W0, W1, W2,
                                                  minv, maxv, out, N);
}

// Round 2
// 272.477 us; speedup vs baseline: 1.0182x; 1.0182x over previous
//
#include <hip/hip_runtime.h>
#include <hip/hip_bf16.h>
#include <math.h>

// MLPTexture3D: 5-level dense-grid trilinear encoding (2 feats/level -> 10)
// + MLP 10->32->32->3 via v_mfma_f32_32x32x16_bf16, per-wave (64 points).
//
// MFMA layouts (gfx950, HW-verified per guide):
//   A[row=lane&31][k=8*(lane>>5)+e]   (short8 = 8 bf16)
//   B[k=8*(lane>>5)+e][col=lane&31]
//   D: col=lane&31, row=(reg&3)+8*(reg>>2)+4*(lane>>5), reg in [0,16)
// Lanes l and l+32 hold complementary row-halves of the SAME column ->
// one v_permlane32_swap_b32 per dword pair converts D-layout to B-layout.

namespace {

typedef __attribute__((ext_vector_type(8)))  short short8;
typedef __attribute__((ext_vector_type(16))) float f32x16;

union S8 { short8 v; int d[4]; };

#define SWAP32(a, b) asm volatile("v_permlane32_swap_b32 %0, %1" : "+v"(a), "+v"(b))

__device__ __forceinline__ int cvt_pk(float lo, float hi) {
    int d;
    asm("v_cvt_pk_bf16_f32 %0, %1, %2" : "=v"(d) : "v"(lo), "v"(hi));
    return d;
}

__device__ __forceinline__ short8 pack8(float4 a, float4 b) {
    S8 u;
    u.d[0] = cvt_pk(a.x, a.y);
    u.d[1] = cvt_pk(a.z, a.w);
    u.d[2] = cvt_pk(b.x, b.y);
    u.d[3] = cvt_pk(b.z, b.w);
    return u.v;
}

__device__ __forceinline__ float clamp01(float v) {
    return fminf(fmaxf(v, 0.0f), 1.0f);
}

// relu(acc f32x16 D-tile) -> two B fragments (k-steps 0 and 1) for next layer
__device__ __forceinline__ void marshal_h(const f32x16& acc, short8& k0, short8& k1) {
    int q[8];
    #pragma unroll
    for (int j = 0; j < 8; ++j) {
        float lo = fmaxf(acc[2*j],   0.0f);
        float hi = fmaxf(acc[2*j+1], 0.0f);
        q[j] = cvt_pk(lo, hi);
    }
    int a0 = q[0], b0 = q[2]; SWAP32(a0, b0);
    int a1 = q[1], b1 = q[3]; SWAP32(a1, b1);
    int a2 = q[4], b2 = q[6]; SWAP32(a2, b2);
    int a3 = q[5], b3 = q[7]; SWAP32(a3, b3);
    S8 u0; u0.d[0] = a0; u0.d[1] = a1; u0.d[2] = b0; u0.d[3] = b1; k0 = u0.v;
    S8 u1; u1.d[0] = a2; u1.d[1] = a3; u1.d[2] = b2; u1.d[3] = b3; k1 = u1.v;
}

__global__ __launch_bounds__(256) void mlptex_kernel(
    const float* __restrict__ texc,
    const float* __restrict__ table,   // [533601,2]
    const float* __restrict__ W0,      // [32,10]
    const float* __restrict__ W1,      // [32,32]
    const float* __restrict__ W2,      // [3,32]
    const float* __restrict__ minv,    // [3]
    const float* __restrict__ maxv,    // [3]
    float* __restrict__ out,           // [N,3]
    int N)
{
    const int tid  = blockIdx.x * blockDim.x + threadIdx.x;
    const int lane = threadIdx.x & 63;
    const int pt   = min(tid, N - 1);         // clamp so permlanes see valid data
    const bool live = (tid < N);

    const int row = lane & 31;
    const int kb  = lane >> 5;

    // ---- one-time per-thread weight fragments (A operands, bf16) ----
    short8 w0f, w1f0, w1f1;
    {
        // W0 row-major [32][10]; kb=0 -> cols 0..7; kb=1 -> cols 8,9 then zero
        const float* p0 = W0 + row * 10;
        float4 a, b;
        if (kb == 0) {
            float2 f0 = *(const float2*)(p0 + 0);
            float2 f1 = *(const float2*)(p0 + 2);
            float2 f2 = *(const float2*)(p0 + 4);
            float2 f3 = *(const float2*)(p0 + 6);
            a = make_float4(f0.x, f0.y, f1.x, f1.y);
            b = make_float4(f2.x, f2.y, f3.x, f3.y);
        } else {
            float2 f4 = *(const float2*)(p0 + 8);
            a = make_float4(f4.x, f4.y, 0.f, 0.f);
            b = make_float4(0.f, 0.f, 0.f, 0.f);
        }
        w0f = pack8(a, b);

        const float* p1 = W1 + row * 32 + kb * 8;
        w1f0 = pack8(*(const float4*)(p1),      *(const float4*)(p1 + 4));
        w1f1 = pack8(*(const float4*)(p1 + 16), *(const float4*)(p1 + 20));
    }
    short8 w2f0 = {0,0,0,0,0,0,0,0}, w2f1 = {0,0,0,0,0,0,0,0};
    if (row < 3) {
        const float* p2 = W2 + row * 32 + kb * 8;
        w2f0 = pack8(*(const float4*)(p2),      *(const float4*)(p2 + 4));
        w2f1 = pack8(*(const float4*)(p2 + 16), *(const float4*)(p2 + 20));
    }

    // ---- encoding (per-thread, unchanged math) ----
    float3 t3 = *(const float3*)(texc + 3 * pt);
    float x = clamp01((t3.x - 0.6f) * (-1.0f/1.4f));
    float y = clamp01((t3.y - 0.6f) * (-1.0f/1.8f));
    float z = clamp01((t3.z - 0.2f) * (-1.0f/0.4f));

    const float2* __restrict__ tab = reinterpret_cast<const float2*>(table);
    const int RESL[5]  = {16, 23, 33, 48, 70};
    const int OFFSL[5] = {0, 4913, 18737, 58041, 175690};

    float p[10];
    #pragma unroll
    for (int l = 0; l < 5; ++l) {
        const int r = RESL[l];
        const int g = r + 1;
        const float rf = (float)r;
        float px = x * rf, py = y * rf, pz = z * rf;
        float fx = fminf(floorf(px), rf - 1.0f);
        float fy = fminf(floorf(py), rf - 1.0f);
        float fz = fminf(floorf(pz), rf - 1.0f);
        float tx = px - fx, ty = py - fy, tz = pz - fz;
        int ix = (int)fx & 127, iy = (int)fy & 127, iz = (int)fz & 127;
        int base = (ix * g + iy) * g + iz + OFFSL[l];

        float2 c000 = tab[base];
        float2 c001 = tab[base + 1];
        float2 c010 = tab[base + g];
        float2 c011 = tab[base + g + 1];
        float2 c100 = tab[base + g*g];
        float2 c101 = tab[base + g*g + 1];
        float2 c110 = tab[base + g*g + g];
        float2 c111 = tab[base + g*g + g + 1];

        float sx = 1.0f - tx, sy = 1.0f - ty, sz = 1.0f - tz;
        float w00 = sy*sz, w01 = sy*tz, w10 = ty*sz, w11 = ty*tz;
        float a00 = sx*w00, a01 = sx*w01, a10 = sx*w10, a11 = sx*w11;
        float b00 = tx*w00, b01 = tx*w01, b10 = tx*w10, b11 = tx*w11;

        float f0, f1;
        f0  = a00*c000.x;            f1  = a00*c000.y;
        f0  = fmaf(a01, c001.x, f0); f1  = fmaf(a01, c001.y, f1);
        f0  = fmaf(a10, c010.x, f0); f1  = fmaf(a10, c010.y, f1);
        f0  = fmaf(a11, c011.x, f0); f1  = fmaf(a11, c011.y, f1);
        f0  = fmaf(b00, c100.x, f0); f1  = fmaf(b00, c100.y, f1);
        f0  = fmaf(b01, c101.x, f0); f1  = fmaf(b01, c101.y, f1);
        f0  = fmaf(b10, c110.x, f0); f1  = fmaf(b10, c110.y, f1);
        f0  = fmaf(b11, c111.x, f0); f1  = fmaf(b11, c111.y, f1);
        p[2*l+0] = f0;
        p[2*l+1] = f1;
    }

    // ---- p[10] -> layer-0 B fragments for both 32-point tiles ----
    int pk0 = cvt_pk(p[0], p[1]);
    int pk1 = cvt_pk(p[2], p[3]);
    int pk2 = cvt_pk(p[4], p[5]);
    int pk3 = cvt_pk(p[6], p[7]);
    int pk4 = cvt_pk(p[8], p[9]);

    int n1d0 = pk0, n2d0 = pk4; SWAP32(n1d0, n2d0);
    int n1d1 = pk1, n2d1 = 0;   SWAP32(n1d1, n2d1);
    int n1d2 = pk2, n2d2 = 0;   SWAP32(n1d2, n2d2);
    int n1d3 = pk3, n2d3 = 0;   SWAP32(n1d3, n2d3);
    S8 ub1; ub1.d[0]=n1d0; ub1.d[1]=n1d1; ub1.d[2]=n1d2; ub1.d[3]=n1d3;
    S8 ub2; ub2.d[0]=n2d0; ub2.d[1]=n2d1; ub2.d[2]=n2d2; ub2.d[3]=n2d3;

    const f32x16 zero16 = {0.f,0.f,0.f,0.f,0.f,0.f,0.f,0.f,
                           0.f,0.f,0.f,0.f,0.f,0.f,0.f,0.f};

    // ---- layer 0: h0 = relu(W0 @ p), one MFMA per 32-point tile ----
    f32x16 h0a = __builtin_amdgcn_mfma_f32_32x32x16_bf16(w0f, ub1.v, zero16, 0, 0, 0);
    f32x16 h0b = __builtin_amdgcn_mfma_f32_32x32x16_bf16(w0f, ub2.v, zero16, 0, 0, 0);

    // ---- layer 1: h1 = relu(W1 @ h0), K=32 -> 2 MFMAs per tile ----
    short8 h0a_k0, h0a_k1, h0b_k0, h0b_k1;
    marshal_h(h0a, h0a_k0, h0a_k1);
    marshal_h(h0b, h0b_k0, h0b_k1);

    f32x16 h1a = __builtin_amdgcn_mfma_f32_32x32x16_bf16(w1f0, h0a_k0, zero16, 0, 0, 0);
    h1a = __builtin_amdgcn_mfma_f32_32x32x16_bf16(w1f1, h0a_k1, h1a, 0, 0, 0);
    f32x16 h1b = __builtin_amdgcn_mfma_f32_32x32x16_bf16(w1f0, h0b_k0, zero16, 0, 0, 0);
    h1b = __builtin_amdgcn_mfma_f32_32x32x16_bf16(w1f1, h0b_k1, h1b, 0, 0, 0);

    // ---- layer 2: o = W2 @ h1 (rows 3..31 zero-padded) ----
    short8 h1a_k0, h1a_k1, h1b_k0, h1b_k1;
    marshal_h(h1a, h1a_k0, h1a_k1);
    marshal_h(h1b, h1b_k0, h1b_k1);

    f32x16 oa = __builtin_amdgcn_mfma_f32_32x32x16_bf16(w2f0, h1a_k0, zero16, 0, 0, 0);
    oa = __builtin_amdgcn_mfma_f32_32x32x16_bf16(w2f1, h1a_k1, oa, 0, 0, 0);
    f32x16 ob = __builtin_amdgcn_mfma_f32_32x32x16_bf16(w2f0, h1b_k0, zero16, 0, 0, 0);
    ob = __builtin_amdgcn_mfma_f32_32x32x16_bf16(w2f1, h1b_k1, ob, 0, 0, 0);

    // ---- epilogue ----
    // oa/ob: rows 0..2 live in lanes<32 (regs 0..2), col = lane&31.
    // Move ob's outputs to the upper lanes so every lane owns point (wavebase+lane).
    float mn[3] = {minv[0], minv[1], minv[2]};
    float sc[3] = {maxv[0] - minv[0], maxv[1] - minv[1], maxv[2] - minv[2]};

    float o[3];
    #pragma unroll
    for (int j = 0; j < 3; ++j) {
        float t0 = ob[j], t1 = ob[j];
        SWAP32(t0, t1);                       // t0: upper lanes get partner's ob[j]
        float v = (lane < 32) ? oa[j] : t0;
        float s = 1.0f / (1.0f + __expf(-v));
        o[j] = fmaf(s, sc[j], mn[j]);
    }

    if (live) {
        float* op = out + 3 * tid;
        op[0] = o[0];
        op[1] = o[1];
        op[2] = o[2];
    }
}

} // anonymous namespace

extern "C" void kernel_launch(void* const* d_in, const int* in_sizes, int n_in,
                              void* d_out, int out_size, void* d_ws, size_t ws_size,
                              hipStream_t stream) {
    const float* texc  = (const float*)d_in[0];
    const float* table = (const float*)d_in[1];
    const float* W0    = (const float*)d_in[2];
    const float* W1    = (const float*)d_in[3];
    const float* W2    = (const float*)d_in[4];
    const float* minv  = (const float*)d_in[5];
    const float* maxv  = (const float*)d_in[6];
    float* out = (float*)d_out;

    const int N = in_sizes[0] / 3;   // 4,194,304 points
    const int threads = 256;
    const int blocks = (N + threads - 1) / threads;
    mlptex_kernel<<<blocks, threads, 0, stream>>>(texc, table, W0, W1, W2,
                                                  minv, maxv, out, N);
}

// Round 3
// 270.537 us; speedup vs baseline: 1.0255x; 1.0072x over previous
//
#include <hip/hip_runtime.h>
#include <hip/hip_bf16.h>
#include <math.h>

// MLPTexture3D: 5-level dense-grid trilinear encoding (2 feats/level -> 10)
// + MLP 10->32->32->3 via v_mfma_f32_32x32x16_bf16, per-wave (64 points).
//
// Round-3 change: corner-pair gathers merged to dwordx4 (20 gathers/point,
// was 40) -- the kernel is gather-transaction-bound, not VALU/MFMA/HBM-bound.
//
// MFMA layouts (gfx950, HW-verified per guide):
//   A[row=lane&31][k=8*(lane>>5)+e]   (short8 = 8 bf16)
//   B[k=8*(lane>>5)+e][col=lane&31]
//   D: col=lane&31, row=(reg&3)+8*(reg>>2)+4*(lane>>5), reg in [0,16)
// Lanes l and l+32 hold complementary row-halves of the SAME column ->
// one v_permlane32_swap_b32 per dword pair converts D-layout to B-layout.

namespace {

typedef __attribute__((ext_vector_type(8)))  short short8;
typedef __attribute__((ext_vector_type(16))) float f32x16;
typedef __attribute__((ext_vector_type(4), aligned(8))) float f32x4a; // 8B-aligned 16B load

union S8 { short8 v; int d[4]; };

#define SWAP32(a, b) asm volatile("v_permlane32_swap_b32 %0, %1" : "+v"(a), "+v"(b))

__device__ __forceinline__ int cvt_pk(float lo, float hi) {
    int d;
    asm("v_cvt_pk_bf16_f32 %0, %1, %2" : "=v"(d) : "v"(lo), "v"(hi));
    return d;
}

__device__ __forceinline__ short8 pack8(float4 a, float4 b) {
    S8 u;
    u.d[0] = cvt_pk(a.x, a.y);
    u.d[1] = cvt_pk(a.z, a.w);
    u.d[2] = cvt_pk(b.x, b.y);
    u.d[3] = cvt_pk(b.z, b.w);
    return u.v;
}

__device__ __forceinline__ float clamp01(float v) {
    return fminf(fmaxf(v, 0.0f), 1.0f);
}

// relu(acc f32x16 D-tile) -> two B fragments (k-steps 0 and 1) for next layer
__device__ __forceinline__ void marshal_h(const f32x16& acc, short8& k0, short8& k1) {
    int q[8];
    #pragma unroll
    for (int j = 0; j < 8; ++j) {
        float lo = fmaxf(acc[2*j],   0.0f);
        float hi = fmaxf(acc[2*j+1], 0.0f);
        q[j] = cvt_pk(lo, hi);
    }
    int a0 = q[0], b0 = q[2]; SWAP32(a0, b0);
    int a1 = q[1], b1 = q[3]; SWAP32(a1, b1);
    int a2 = q[4], b2 = q[6]; SWAP32(a2, b2);
    int a3 = q[5], b3 = q[7]; SWAP32(a3, b3);
    S8 u0; u0.d[0] = a0; u0.d[1] = a1; u0.d[2] = b0; u0.d[3] = b1; k0 = u0.v;
    S8 u1; u1.d[0] = a2; u1.d[1] = a3; u1.d[2] = b2; u1.d[3] = b3; k1 = u1.v;
}

__global__ __launch_bounds__(256) void mlptex_kernel(
    const float* __restrict__ texc,
    const float* __restrict__ table,   // [533601,2]
    const float* __restrict__ W0,      // [32,10]
    const float* __restrict__ W1,      // [32,32]
    const float* __restrict__ W2,      // [3,32]
    const float* __restrict__ minv,    // [3]
    const float* __restrict__ maxv,    // [3]
    float* __restrict__ out,           // [N,3]
    int N)
{
    const int tid  = blockIdx.x * blockDim.x + threadIdx.x;
    const int lane = threadIdx.x & 63;
    const int pt   = min(tid, N - 1);         // clamp so permlanes see valid data
    const bool live = (tid < N);

    const int row = lane & 31;
    const int kb  = lane >> 5;

    // ---- one-time per-thread weight fragments (A operands, bf16) ----
    short8 w0f, w1f0, w1f1;
    {
        // W0 row-major [32][10]; kb=0 -> cols 0..7; kb=1 -> cols 8,9 then zero
        const float* p0 = W0 + row * 10;
        float4 a, b;
        if (kb == 0) {
            float2 f0 = *(const float2*)(p0 + 0);
            float2 f1 = *(const float2*)(p0 + 2);
            float2 f2 = *(const float2*)(p0 + 4);
            float2 f3 = *(const float2*)(p0 + 6);
            a = make_float4(f0.x, f0.y, f1.x, f1.y);
            b = make_float4(f2.x, f2.y, f3.x, f3.y);
        } else {
            float2 f4 = *(const float2*)(p0 + 8);
            a = make_float4(f4.x, f4.y, 0.f, 0.f);
            b = make_float4(0.f, 0.f, 0.f, 0.f);
        }
        w0f = pack8(a, b);

        const float* p1 = W1 + row * 32 + kb * 8;
        w1f0 = pack8(*(const float4*)(p1),      *(const float4*)(p1 + 4));
        w1f1 = pack8(*(const float4*)(p1 + 16), *(const float4*)(p1 + 20));
    }
    short8 w2f0 = {0,0,0,0,0,0,0,0}, w2f1 = {0,0,0,0,0,0,0,0};
    if (row < 3) {
        const float* p2 = W2 + row * 32 + kb * 8;
        w2f0 = pack8(*(const float4*)(p2),      *(const float4*)(p2 + 4));
        w2f1 = pack8(*(const float4*)(p2 + 16), *(const float4*)(p2 + 20));
    }

    // ---- encoding (per-thread) ----
    float3 t3 = *(const float3*)(texc + 3 * pt);
    float x = clamp01((t3.x - 0.6f) * (-1.0f/1.4f));
    float y = clamp01((t3.y - 0.6f) * (-1.0f/1.8f));
    float z = clamp01((t3.z - 0.2f) * (-1.0f/0.4f));

    const float2* __restrict__ tab = reinterpret_cast<const float2*>(table);
    const int RESL[5]  = {16, 23, 33, 48, 70};
    const int OFFSL[5] = {0, 4913, 18737, 58041, 175690};

    float p[10];
    #pragma unroll
    for (int l = 0; l < 5; ++l) {
        const int r = RESL[l];
        const int g = r + 1;
        const float rf = (float)r;
        float px = x * rf, py = y * rf, pz = z * rf;
        float fx = fminf(floorf(px), rf - 1.0f);
        float fy = fminf(floorf(py), rf - 1.0f);
        float fz = fminf(floorf(pz), rf - 1.0f);
        float tx = px - fx, ty = py - fy, tz = pz - fz;
        int ix = (int)fx & 127, iy = (int)fy & 127, iz = (int)fz & 127;
        int base = (ix * g + iy) * g + iz + OFFSL[l];

        // 4 merged corner-pair fetches (dwordx4 each; 8B-aligned is legal)
        f32x4a q00 = *reinterpret_cast<const f32x4a*>(tab + base);           // c000|c001
        f32x4a q01 = *reinterpret_cast<const f32x4a*>(tab + base + g);       // c010|c011
        f32x4a q10 = *reinterpret_cast<const f32x4a*>(tab + base + g*g);     // c100|c101
        f32x4a q11 = *reinterpret_cast<const f32x4a*>(tab + base + g*g + g); // c110|c111

        float sx = 1.0f - tx, sy = 1.0f - ty, sz = 1.0f - tz;
        float w00 = sy*sz, w01 = sy*tz, w10 = ty*sz, w11 = ty*tz;
        float a00 = sx*w00, a01 = sx*w01, a10 = sx*w10, a11 = sx*w11;
        float b00 = tx*w00, b01 = tx*w01, b10 = tx*w10, b11 = tx*w11;

        float f0, f1;
        f0  = a00*q00[0];            f1  = a00*q00[1];
        f0  = fmaf(a01, q00[2], f0); f1  = fmaf(a01, q00[3], f1);
        f0  = fmaf(a10, q01[0], f0); f1  = fmaf(a10, q01[1], f1);
        f0  = fmaf(a11, q01[2], f0); f1  = fmaf(a11, q01[3], f1);
        f0  = fmaf(b00, q10[0], f0); f1  = fmaf(b00, q10[1], f1);
        f0  = fmaf(b01, q10[2], f0); f1  = fmaf(b01, q10[3], f1);
        f0  = fmaf(b10, q11[0], f0); f1  = fmaf(b10, q11[1], f1);
        f0  = fmaf(b11, q11[2], f0); f1  = fmaf(b11, q11[3], f1);
        p[2*l+0] = f0;
        p[2*l+1] = f1;
    }

    // ---- p[10] -> layer-0 B fragments for both 32-point tiles ----
    int pk0 = cvt_pk(p[0], p[1]);
    int pk1 = cvt_pk(p[2], p[3]);
    int pk2 = cvt_pk(p[4], p[5]);
    int pk3 = cvt_pk(p[6], p[7]);
    int pk4 = cvt_pk(p[8], p[9]);

    int n1d0 = pk0, n2d0 = pk4; SWAP32(n1d0, n2d0);
    int n1d1 = pk1, n2d1 = 0;   SWAP32(n1d1, n2d1);
    int n1d2 = pk2, n2d2 = 0;   SWAP32(n1d2, n2d2);
    int n1d3 = pk3, n2d3 = 0;   SWAP32(n1d3, n2d3);
    S8 ub1; ub1.d[0]=n1d0; ub1.d[1]=n1d1; ub1.d[2]=n1d2; ub1.d[3]=n1d3;
    S8 ub2; ub2.d[0]=n2d0; ub2.d[1]=n2d1; ub2.d[2]=n2d2; ub2.d[3]=n2d3;

    const f32x16 zero16 = {0.f,0.f,0.f,0.f,0.f,0.f,0.f,0.f,
                           0.f,0.f,0.f,0.f,0.f,0.f,0.f,0.f};

    // ---- layer 0: h0 = relu(W0 @ p) ----
    f32x16 h0a = __builtin_amdgcn_mfma_f32_32x32x16_bf16(w0f, ub1.v, zero16, 0, 0, 0);
    f32x16 h0b = __builtin_amdgcn_mfma_f32_32x32x16_bf16(w0f, ub2.v, zero16, 0, 0, 0);

    // ---- layer 1: h1 = relu(W1 @ h0), K=32 -> 2 MFMAs per tile ----
    short8 h0a_k0, h0a_k1, h0b_k0, h0b_k1;
    marshal_h(h0a, h0a_k0, h0a_k1);
    marshal_h(h0b, h0b_k0, h0b_k1);

    f32x16 h1a = __builtin_amdgcn_mfma_f32_32x32x16_bf16(w1f0, h0a_k0, zero16, 0, 0, 0);
    h1a = __builtin_amdgcn_mfma_f32_32x32x16_bf16(w1f1, h0a_k1, h1a, 0, 0, 0);
    f32x16 h1b = __builtin_amdgcn_mfma_f32_32x32x16_bf16(w1f0, h0b_k0, zero16, 0, 0, 0);
    h1b = __builtin_amdgcn_mfma_f32_32x32x16_bf16(w1f1, h0b_k1, h1b, 0, 0, 0);

    // ---- layer 2: o = W2 @ h1 (rows 3..31 zero-padded) ----
    short8 h1a_k0, h1a_k1, h1b_k0, h1b_k1;
    marshal_h(h1a, h1a_k0, h1a_k1);
    marshal_h(h1b, h1b_k0, h1b_k1);

    f32x16 oa = __builtin_amdgcn_mfma_f32_32x32x16_bf16(w2f0, h1a_k0, zero16, 0, 0, 0);
    oa = __builtin_amdgcn_mfma_f32_32x32x16_bf16(w2f1, h1a_k1, oa, 0, 0, 0);
    f32x16 ob = __builtin_amdgcn_mfma_f32_32x32x16_bf16(w2f0, h1b_k0, zero16, 0, 0, 0);
    ob = __builtin_amdgcn_mfma_f32_32x32x16_bf16(w2f1, h1b_k1, ob, 0, 0, 0);

    // ---- epilogue ----
    float mn[3] = {minv[0], minv[1], minv[2]};
    float sc[3] = {maxv[0] - minv[0], maxv[1] - minv[1], maxv[2] - minv[2]};

    float o[3];
    #pragma unroll
    for (int j = 0; j < 3; ++j) {
        float t0 = ob[j], t1 = ob[j];
        SWAP32(t0, t1);                       // upper lanes get partner's ob[j]
        float v = (lane < 32) ? oa[j] : t0;
        float s = 1.0f / (1.0f + __expf(-v));
        o[j] = fmaf(s, sc[j], mn[j]);
    }

    if (live) {
        *reinterpret_cast<float3*>(out + 3 * tid) = make_float3(o[0], o[1], o[2]);
    }
}

} // anonymous namespace

extern "C" void kernel_launch(void* const* d_in, const int* in_sizes, int n_in,
                              void* d_out, int out_size, void* d_ws, size_t ws_size,
                              hipStream_t stream) {
    const float* texc  = (const float*)d_in[0];
    const float* table = (const float*)d_in[1];
    const float* W0    = (const float*)d_in[2];
    const float* W1    = (const float*)d_in[3];
    const float* W2    = (const float*)d_in[4];
    const float* minv  = (const float*)d_in[5];
    const float* maxv  = (const float*)d_in[6];
    float* out = (float*)d_out;

    const int N = in_sizes[0] / 3;   // 4,194,304 points
    const int threads = 256;
    const int blocks = (N + threads - 1) / threads;
    mlptex_kernel<<<blocks, threads, 0, stream>>>(texc, table, W0, W1, W2,
                                                  minv, maxv, out, N);
}